// Round 16
// baseline (310.739 us; speedup 1.0000x reference)
//
#include <hip/hip_runtime.h>
#include <stdint.h>

#define B_SZ 2
#define S_LEN 2048
#define D_DIM 2048
#define NHEAD 16
#define HD 128
#define HALF 64
#define MROWS (B_SZ * S_LEN)   // 4096

typedef __attribute__((ext_vector_type(8))) __bf16 bf16x8;
typedef __attribute__((ext_vector_type(8))) unsigned short u16x8;
typedef __attribute__((ext_vector_type(4))) float f32x4;
typedef __attribute__((ext_vector_type(16))) float f32x16;
typedef __attribute__((ext_vector_type(4))) unsigned int u32x4;

__device__ inline unsigned short f2bf(float x) {
  union { float f; uint32_t u; } c; c.f = x;
  uint32_t r = (c.u + 0x7fffu + ((c.u >> 16) & 1u)) >> 16;
  return (unsigned short)r;
}

__device__ inline float bf2f(unsigned short b) {
  union { uint32_t u; float f; } c; c.u = (uint32_t)b << 16;
  return c.f;
}

__device__ inline void gll16(const void* g, void* l) {
  __builtin_amdgcn_global_load_lds(
      (const __attribute__((address_space(1))) void*)g,
      (__attribute__((address_space(3))) void*)l,
      16, 0, 0);
}

#define SB __builtin_amdgcn_sched_barrier(0)

// ---------------- fused cast f32 -> bf16 for x + 4 weight matrices ----------------
__global__ void cast_all(const float* __restrict__ x,
                         const float* __restrict__ qw, const float* __restrict__ kw,
                         const float* __restrict__ vw, const float* __restrict__ ow,
                         unsigned short* __restrict__ xb,
                         unsigned short* __restrict__ qwb, unsigned short* __restrict__ kwb,
                         unsigned short* __restrict__ vwb, unsigned short* __restrict__ owb) {
  const int n_x = (MROWS * D_DIM) / 4;
  const int n_w = (D_DIM * D_DIM) / 4;      // == 1<<20
  const int total = n_x + 4 * n_w;
  int i = blockIdx.x * blockDim.x + threadIdx.x;
  int stride = gridDim.x * blockDim.x;
  for (; i < total; i += stride) {
    const float* src; unsigned short* dst; int off;
    if (i < n_x) { src = x; dst = xb; off = i; }
    else {
      int j = i - n_x;
      int seg = j >> 20;
      off = j & (n_w - 1);
      src = seg == 0 ? qw : seg == 1 ? kw : seg == 2 ? vw : ow;
      dst = seg == 0 ? qwb : seg == 1 ? kwb : seg == 2 ? vwb : owb;
    }
    float4 v = reinterpret_cast<const float4*>(src)[off];
    ushort4 o;
    o.x = f2bf(v.x); o.y = f2bf(v.y); o.z = f2bf(v.z); o.w = f2bf(v.w);
    reinterpret_cast<ushort4*>(dst)[off] = o;
  }
}

// ---------------- QKV GEMM: 256x256 tile, BK=64, 8 waves, 4-phase interleave ----------------
// C[i,j] = sum_k A[i,k]*Bt[j,k] + bias[j], N=6144 fused-QKV epilogue (seg0->C0
// bf16, seg1->C1 bf16, seg2->C2 = Vt2[b][h][s/64][d][s%64]).
// T2+T3+T4+T5 port: per K-tile, 4 phases of {8 ds_read_b128 quadrant ||
// stage 1 half-tile (2 gll16) -> s_barrier -> setprio + 16 MFMA + setprio ->
// s_barrier}; vmcnt(2) once per K-tile at phase 0 (tile t+1's 8 loads drain
// while tile t+2's first pair stays in flight -> never a full drain).
// LDS 128KB: A/B each 2dbuf x 2half x 128x64 bf16. Swizzle chunk^=(row&7)
// (proven involution, 0 bank conflicts in round 15).
__global__ __launch_bounds__(512) void gemm256q(
    const unsigned short* __restrict__ A, const unsigned short* __restrict__ Bt,
    const float* __restrict__ bias, unsigned short* __restrict__ C0,
    unsigned short* __restrict__ C1, unsigned short* __restrict__ C2,
    int M, int N, int K) {
  __shared__ __align__(16) unsigned short Asq[2 * 2 * 128 * 64];  // 64KB
  __shared__ __align__(16) unsigned short Bsq[2 * 2 * 128 * 64];  // 64KB
  const int tid = threadIdx.x;
  const int lane = tid & 63;
  const int wave = tid >> 6;            // 0..7
  const int wr = wave >> 2;             // 0..1 (m-half)
  const int wc = wave & 3;              // 0..3 (n quarter)
  const int lm = lane & 15, lg = lane >> 4;
  const int xcd = blockIdx.x & 7;
  const int w = blockIdx.x >> 3;
  const int bm = w & 15;                             // M=4096 -> 16 bm panels
  const int bn = xcd * ((N >> 8) >> 3) + (w >> 4);   // bn-major per XCD

  // stage source pointers (swizzled global col), fixed; +k0 at issue
  const int pb0 = tid * 16, pb1 = tid * 16 + 8192;
  const int r0 = pb0 >> 7, s0_ = (((pb0 >> 4) & 7) ^ (r0 & 7)) << 3;
  const int r1 = pb1 >> 7, s1_ = (((pb1 >> 4) & 7) ^ (r1 & 7)) << 3;
  const unsigned short* A00 = A + (size_t)(bm * 256 + r0) * K + s0_;
  const unsigned short* A01 = A + (size_t)(bm * 256 + r1) * K + s1_;
  const unsigned short* A10 = A + (size_t)(bm * 256 + 128 + r0) * K + s0_;
  const unsigned short* A11 = A + (size_t)(bm * 256 + 128 + r1) * K + s1_;
  const unsigned short* B00 = Bt + (size_t)(bn * 256 + r0) * K + s0_;
  const unsigned short* B01 = Bt + (size_t)(bn * 256 + r1) * K + s1_;
  const unsigned short* B10 = Bt + (size_t)(bn * 256 + 128 + r0) * K + s0_;
  const unsigned short* B11 = Bt + (size_t)(bn * 256 + 128 + r1) * K + s1_;

  f32x4 acc[8][4] = {};

#define LOADQ(KK, MQ, AF, BF)                                                  \
  _Pragma("unroll") for (int i = 0; i < 4; ++i) {                              \
    int rra = (MQ)*64 + i * 16 + lm;                                           \
    AF[i] = *reinterpret_cast<const bf16x8*>((const char*)Asq + cur * 32768 +  \
        wr * 16384 + rra * 128 + ((((KK)*4 + lg) ^ (rra & 7)) << 4));          \
  }                                                                            \
  _Pragma("unroll") for (int j = 0; j < 4; ++j) {                              \
    int rrb = (wc & 1) * 64 + j * 16 + lm;                                     \
    BF[j] = *reinterpret_cast<const bf16x8*>((const char*)Bsq + cur * 32768 +  \
        (wc >> 1) * 16384 + rrb * 128 + ((((KK)*4 + lg) ^ (rrb & 7)) << 4));   \
  }

#define MFMA16(MQ, AF, BF)                                                     \
  __builtin_amdgcn_s_setprio(1);                                               \
  _Pragma("unroll") for (int i = 0; i < 4; ++i)                                \
    _Pragma("unroll") for (int j = 0; j < 4; ++j)                              \
      acc[(MQ)*4 + i][j] = __builtin_amdgcn_mfma_f32_16x16x32_bf16(            \
          AF[i], BF[j], acc[(MQ)*4 + i][j], 0, 0, 0);                          \
  __builtin_amdgcn_s_setprio(0)

#define BARRIER  SB; __builtin_amdgcn_s_barrier(); SB

  const int NT = K >> 6;   // 32
  // prologue: stage tile 0 into buf 0 (8 loads)
  gll16(A00, (char*)Asq + pb0);          gll16(A01, (char*)Asq + pb1);
  gll16(A10, (char*)Asq + 16384 + pb0);  gll16(A11, (char*)Asq + 16384 + pb1);
  gll16(B00, (char*)Bsq + pb0);          gll16(B01, (char*)Bsq + pb1);
  gll16(B10, (char*)Bsq + 16384 + pb0);  gll16(B11, (char*)Bsq + 16384 + pb1);

  for (int t = 0; t < NT; ++t) {
    const int cur = t & 1;
    const int sb = (cur ^ 1) * 32768;
    const int koff = ((t + 1 < NT) ? t + 1 : t) << 6;

    // ---- phase 0: stage A-half0(t+1); vmcnt(2); ds_read (kk0,mq0); MFMA
    gll16(A00 + koff, (char*)Asq + sb + pb0);
    gll16(A01 + koff, (char*)Asq + sb + pb1);
    asm volatile("s_waitcnt vmcnt(2)" ::: "memory");
    BARRIER;
    {
      bf16x8 af[4], bf[4];
      LOADQ(0, 0, af, bf);
      MFMA16(0, af, bf);
    }
    BARRIER;
    // ---- phase 1: ds_read (kk0,mq1); stage A-half1(t+1); MFMA
    {
      bf16x8 af[4], bf[4];
      LOADQ(0, 1, af, bf);
      gll16(A10 + koff, (char*)Asq + sb + 16384 + pb0);
      gll16(A11 + koff, (char*)Asq + sb + 16384 + pb1);
      BARRIER;
      MFMA16(1, af, bf);
    }
    BARRIER;
    // ---- phase 2: ds_read (kk1,mq0); stage B-half0(t+1); MFMA
    {
      bf16x8 af[4], bf[4];
      LOADQ(1, 0, af, bf);
      gll16(B00 + koff, (char*)Bsq + sb + pb0);
      gll16(B01 + koff, (char*)Bsq + sb + pb1);
      BARRIER;
      MFMA16(0, af, bf);
    }
    BARRIER;
    // ---- phase 3: ds_read (kk1,mq1); stage B-half1(t+1); MFMA
    {
      bf16x8 af[4], bf[4];
      LOADQ(1, 1, af, bf);
      gll16(B10 + koff, (char*)Bsq + sb + 16384 + pb0);
      gll16(B11 + koff, (char*)Bsq + sb + 16384 + pb1);
      BARRIER;
      MFMA16(1, af, bf);
    }
    BARRIER;
  }
#undef LOADQ
#undef MFMA16
#undef BARRIER

  // ---------------- epilogue (QKV fused) ----------------
#pragma unroll
  for (int nf = 0; nf < 4; ++nf) {
    int col = bn * 256 + wc * 64 + nf * 16 + lm;
    float bv = bias[col];
    int seg = col >> 11;              // 0=Q, 1=K, 2=V
    int c2 = col & (D_DIM - 1);
#pragma unroll
    for (int mf = 0; mf < 8; ++mf) {
      int row0 = bm * 256 + wr * 128 + mf * 16 + lg * 4;
      if (seg == 2) {
        int b = row0 >> 11, sp = row0 & (S_LEN - 1);
        int h = c2 >> 7, d = c2 & (HD - 1);
        ushort4 o;
        o.x = f2bf(acc[mf][nf][0] + bv);
        o.y = f2bf(acc[mf][nf][1] + bv);
        o.z = f2bf(acc[mf][nf][2] + bv);
        o.w = f2bf(acc[mf][nf][3] + bv);
        size_t oi = ((((size_t)(b * NHEAD + h) * (S_LEN / 64) + (sp >> 6)) * HD + d) << 6)
                    + (sp & 63);
        *reinterpret_cast<ushort4*>(C2 + oi) = o;
      } else {
        unsigned short* dst = (seg == 0) ? C0 : C1;
#pragma unroll
        for (int r = 0; r < 4; ++r)
          dst[(size_t)(row0 + r) * D_DIM + c2] = f2bf(acc[mf][nf][r] + bv);
      }
    }
  }
}

// ---------------- GEMM 128x128 tile, BK=64 + XOR swizzle (O-projection) ----------------
__global__ __launch_bounds__(256) void gemm_bt(
    const unsigned short* __restrict__ A, const unsigned short* __restrict__ Bt,
    const float* __restrict__ bias, float* __restrict__ C0,
    int M, int N, int K) {
  __shared__ __align__(16) unsigned short As[128 * 64];   // 16KB
  __shared__ __align__(16) unsigned short Bs[128 * 64];   // 16KB
  const int tid = threadIdx.x;
  const int lane = tid & 63;
  const int wave = tid >> 6;
  const int nbn = N >> 7;
  const int xcd = blockIdx.x & 7;
  const int w = blockIdx.x >> 3;
  const int bm = w & 31;
  const int bn = xcd * (nbn >> 3) + (w >> 5);
  const int wr = wave >> 1, wc = wave & 1;
  const int lm = lane & 15, lg = lane >> 4;

  f32x4 acc[4][4] = {};

  for (int k0 = 0; k0 < K; k0 += 64) {
    __syncthreads();
#pragma unroll
    for (int r = 0; r < 4; ++r) {
      int p = r * 4096 + tid * 16;
      int row = p >> 7;
      int ch = (p >> 4) & 7;
      int sc = (ch ^ (row & 7)) << 3;
      gll16(A + (size_t)(bm * 128 + row) * K + k0 + sc, (char*)As + p);
      gll16(Bt + (size_t)(bn * 128 + row) * K + k0 + sc, (char*)Bs + p);
    }
    __syncthreads();

#pragma unroll
    for (int kk = 0; kk < 2; ++kk) {
      bf16x8 af[4], bfr[4];
#pragma unroll
      for (int mi = 0; mi < 4; ++mi) {
        int row = wr * 64 + mi * 16 + lm;
        af[mi] = *reinterpret_cast<const bf16x8*>(
            (const char*)As + row * 128 + ((((kk << 2) + lg) ^ (row & 7)) << 4));
      }
#pragma unroll
      for (int ni = 0; ni < 4; ++ni) {
        int row = wc * 64 + ni * 16 + lm;
        bfr[ni] = *reinterpret_cast<const bf16x8*>(
            (const char*)Bs + row * 128 + ((((kk << 2) + lg) ^ (row & 7)) << 4));
      }
#pragma unroll
      for (int mi = 0; mi < 4; ++mi)
#pragma unroll
        for (int ni = 0; ni < 4; ++ni)
          acc[mi][ni] = __builtin_amdgcn_mfma_f32_16x16x32_bf16(
              af[mi], bfr[ni], acc[mi][ni], 0, 0, 0);
    }
  }

#pragma unroll
  for (int ni = 0; ni < 4; ++ni) {
    int col = bn * 128 + wc * 64 + ni * 16 + lm;
    float bv = bias[col];
#pragma unroll
    for (int mi = 0; mi < 4; ++mi) {
      int row0 = bm * 128 + wr * 64 + mi * 16 + lg * 4;
#pragma unroll
      for (int r = 0; r < 4; ++r)
        C0[(size_t)(row0 + r) * N + col] = acc[mi][ni][r] + bv;
    }
  }
}

// ---------------- merged RMSNorm+RoPE for Q (linear out) and K (head-blocked out) ----------------
__global__ __launch_bounds__(256) void norm_rope2(
    const unsigned short* __restrict__ qin, const unsigned short* __restrict__ kin,
    const float* __restrict__ qnw, const float* __restrict__ knw,
    const float* __restrict__ cosb, const float* __restrict__ sinb,
    unsigned short* __restrict__ qout, unsigned short* __restrict__ kout,
    float qscale) {
  const int isK = blockIdx.x >> 12;                // grid = 2*MROWS
  const int row = blockIdx.x & (MROWS - 1);
  const int pos = row & (S_LEN - 1);
  const unsigned short* hr = (isK ? kin : qin) + (size_t)row * D_DIM;
  const float* w = isK ? knw : qnw;
  const float outscale = isK ? 1.0f : qscale;
  const int t = threadIdx.x;
  const int d = t * 8;

  u16x8 hv = *reinterpret_cast<const u16x8*>(hr + d);
  float a[8];
#pragma unroll
  for (int i = 0; i < 8; ++i) a[i] = bf2f(hv[i]);
  float ss = 0.f;
#pragma unroll
  for (int i = 0; i < 8; ++i) ss += a[i] * a[i];
#pragma unroll
  for (int off = 32; off > 0; off >>= 1) ss += __shfl_down(ss, off);
  __shared__ float red[4];
  if ((t & 63) == 0) red[t >> 6] = ss;
  __syncthreads();
  float tot = red[0] + red[1] + red[2] + red[3];
  float inv = rsqrtf(tot * (1.0f / D_DIM) + 1e-6f) * outscale;

  const int p = (d & (HD - 1)) >> 1;
  const float* cp = cosb + pos * HALF + p;
  const float* sp = sinb + pos * HALF + p;
  const float* wp = w + d;

  float c0 = cp[0], c1 = cp[1], c2 = cp[2], c3 = cp[3];
  float s0 = sp[0], s1 = sp[1], s2 = sp[2], s3 = sp[3];
#pragma unroll
  for (int i = 0; i < 8; ++i) a[i] = a[i] * inv * wp[i];
  u16x8 o;
  o[0] = f2bf(a[0] * c0 - a[1] * s0);
  o[1] = f2bf(a[0] * s0 + a[1] * c0);
  o[2] = f2bf(a[2] * c1 - a[3] * s1);
  o[3] = f2bf(a[2] * s1 + a[3] * c1);
  o[4] = f2bf(a[4] * c2 - a[5] * s2);
  o[5] = f2bf(a[4] * s2 + a[5] * c2);
  o[6] = f2bf(a[6] * c3 - a[7] * s3);
  o[7] = f2bf(a[6] * s3 + a[7] * c3);
  if (isK) {
    int hh = t >> 4;
    int dd = d & (HD - 1);
    size_t oi = (((size_t)((row >> 11) * NHEAD + hh) * S_LEN) + pos) * HD + dd;
    *reinterpret_cast<u16x8*>(kout + oi) = o;
  } else {
    *reinterpret_cast<u16x8*>(qout + (size_t)row * D_DIM + d) = o;
  }
}

// ---------------- flash attention: 8 waves x 32q (QBLK=256), KVBLK=128 ----------------
// (unchanged from round 13-15)
__global__ __launch_bounds__(512) void attn_kernel(
    const unsigned short* __restrict__ Q, const unsigned short* __restrict__ Kh,
    const unsigned short* __restrict__ Vt, unsigned short* __restrict__ O) {
  const int idx = blockIdx.x;
  const int swz = (idx & 7) * 32 + (idx >> 3);   // 256 blocks, 32/XCD (4 heads)
  const int qb = swz & 7;
  const int h = (swz >> 3) & 15;
  const int b = swz >> 7;

  const int tid = threadIdx.x;
  const int lane = tid & 63;
  const int wave = tid >> 6;          // 0..7
  const int l31 = lane & 31;
  const int hh = lane >> 5;

  const size_t qbase = (size_t)b * S_LEN * D_DIM + (size_t)h * HD;   // linear Q/O
  const size_t hbase = (size_t)(b * NHEAD + h) * S_LEN * HD;         // blocked K/V
  const int q0w = qb * 256 + wave * 32;

  __shared__ __align__(16) unsigned short Ks[2 * 128 * 128];  // 2 x 32KB (dbuf)
  __shared__ __align__(16) unsigned short Vs[2 * 128 * 64];   // 32KB (2 s-halves)

  bf16x8 qf[8];
#pragma unroll
  for (int ds_ = 0; ds_ < 8; ++ds_)
    qf[ds_] = *reinterpret_cast<const bf16x8*>(
        Q + qbase + (size_t)(q0w + l31) * D_DIM + ds_ * 16 + hh * 8);

  f32x16 oacc[4] = {};
  float mrow = -1e30f, lrow = 0.f;

  const int pbase = wave * 1024 + (lane << 4);   // + j*8192, j=0..3 -> [0,32768)

  auto stageK = [&](int buf, int tix) {
    const unsigned short* ksrc = Kh + hbase + (size_t)tix * (128 * HD);
#pragma unroll
    for (int j = 0; j < 4; ++j) {
      int p = pbase + j * 8192;
      int kr = p >> 8;                                   // row 0..127 (256B rows)
      int kc = ((p >> 4) & 15) ^ ((kr & 7) ^ ((kr >> 3) & 7));
      gll16(ksrc + kr * 128 + kc * 8, (char*)Ks + buf * 32768 + p);
    }
  };
  auto stageV = [&](int tix) {
    const unsigned short* vsrc = Vt + hbase + (size_t)tix * (128 * HD);  // 2 v-tiles
#pragma unroll
    for (int j = 0; j < 4; ++j) {
      int p = pbase + j * 8192;
      int vr = (p & 16383) >> 7;                         // d-row 0..127 (128B rows)
      int vc = ((p >> 4) & 7) ^ (((vr & 7) ^ ((vr >> 3) & 7)) & 7);
      gll16(vsrc + (p >> 14) * (64 * HD) + vr * 64 + vc * 8, (char*)Vs + p);
    }
  };

  stageK(0, 0);   // 4 K-loads in flight

  const int NT = S_LEN / 128;          // 16
  for (int t = 0; t < NT; ++t) {
    const int cur = t & 1;
    stageV(t);                                          // +4 (V(t))
    stageK(cur ^ 1, (t + 1 < NT) ? t + 1 : t);          // +4 (K(t+1))
    asm volatile("s_waitcnt vmcnt(8)" ::: "memory");    // drain K(t) (oldest 4)
    SB;
    __builtin_amdgcn_s_barrier();          // BAR1: K(t) visible
    SB;

    // ---- QK^T swapped: sc[j] = P[k = 32j..32j+31][q = l31]
    const char* kbp = (const char*)Ks + cur * 32768;
    f32x16 sc[4] = {};
    __builtin_amdgcn_s_setprio(1);
#pragma unroll
    for (int ds_ = 0; ds_ < 8; ++ds_) {
#pragma unroll
      for (int j = 0; j < 4; ++j) {
        int r = j * 32 + l31;
        bf16x8 kf = *reinterpret_cast<const bf16x8*>(
            kbp + r * 256 + (((ds_ * 2 + hh) ^ ((r & 7) ^ ((r >> 3) & 7))) << 4));
        sc[j] = __builtin_amdgcn_mfma_f32_32x32x16_bf16(kf, qf[ds_], sc[j], 0, 0, 0);
      }
    }
    __builtin_amdgcn_s_setprio(0);

    // ---- online softmax (per-lane q-row = l31), tree reductions over 64 vals
    float m0[16];
#pragma unroll
    for (int r = 0; r < 16; ++r)
      m0[r] = fmaxf(fmaxf(sc[0][r], sc[1][r]), fmaxf(sc[2][r], sc[3][r]));
#pragma unroll
    for (int r = 0; r < 8; ++r) m0[r] = fmaxf(m0[r], m0[r + 8]);
#pragma unroll
    for (int r = 0; r < 4; ++r) m0[r] = fmaxf(m0[r], m0[r + 4]);
    float mx = fmaxf(fmaxf(m0[0], m0[1]), fmaxf(m0[2], m0[3]));
    mx = fmaxf(mx, __shfl_xor(mx, 32));
    if (__any(mx > mrow + 8.0f)) {          // defer-max rescale (rare)
      float nm = fmaxf(mrow, mx);
      float alpha = exp2f(mrow - nm);
      mrow = nm;
      lrow *= alpha;
#pragma unroll
      for (int r = 0; r < 16; ++r) {
        int qr = (r & 3) + 8 * (r >> 2) + 4 * hh;
        float av = __shfl(alpha, qr);
        oacc[0][r] *= av; oacc[1][r] *= av; oacc[2][r] *= av; oacc[3][r] *= av;
      }
    }
#pragma unroll
    for (int j = 0; j < 4; ++j)
#pragma unroll
      for (int r = 0; r < 16; ++r) sc[j][r] = exp2f(sc[j][r] - mrow);
    float s0[16];
#pragma unroll
    for (int r = 0; r < 16; ++r)
      s0[r] = (sc[0][r] + sc[1][r]) + (sc[2][r] + sc[3][r]);
#pragma unroll
    for (int r = 0; r < 8; ++r) s0[r] += s0[r + 8];
#pragma unroll
    for (int r = 0; r < 4; ++r) s0[r] += s0[r + 4];
    lrow += (s0[0] + s0[1]) + (s0[2] + s0[3]);

    // ---- P -> bf16 A-frags in-register (cvt_pk + permlane32_swap)
    uint32_t w[32];
#pragma unroll
    for (int X = 0; X < 4; ++X) {
#pragma unroll
      for (int g = 0; g < 4; ++g) {
        uint32_t lo, hi;
        float a0 = sc[X][4 * g], a1 = sc[X][4 * g + 1];
        float a2 = sc[X][4 * g + 2], a3 = sc[X][4 * g + 3];
        asm("v_cvt_pk_bf16_f32 %0, %1, %2" : "=v"(lo) : "v"(a0), "v"(a1));
        asm("v_cvt_pk_bf16_f32 %0, %1, %2" : "=v"(hi) : "v"(a2), "v"(a3));
        w[X * 8 + g * 2] = lo; w[X * 8 + g * 2 + 1] = hi;
      }
    }
    bf16x8 pa[8];
#pragma unroll
    for (int s = 0; s < 8; ++s) {
      int wb = (s >> 1) * 8 + (s & 1) * 4;
      uint32_t le = w[wb], he = w[wb + 1], lo_ = w[wb + 2], ho = w[wb + 3];
      asm("v_permlane32_swap_b32 %0, %1" : "+v"(le), "+v"(lo_));
      asm("v_permlane32_swap_b32 %0, %1" : "+v"(he), "+v"(ho));
      u32x4 fr = {le, he, lo_, ho};
      pa[s] = __builtin_bit_cast(bf16x8, fr);
    }

    // ---- wait V(t) (drains to 4: K(t+1) stays in flight), then barrier
    asm volatile("s_waitcnt vmcnt(4)" ::: "memory");
    SB;
    __builtin_amdgcn_s_barrier();          // BAR-mid: V(t) visible
    SB;

    // ---- PV: O[q][d] += P[q][k] V[k][d], k 0..127 in 8 slots
    const char* vbp = (const char*)Vs;
    __builtin_amdgcn_s_setprio(1);
#pragma unroll
    for (int db = 0; db < 4; ++db) {
      int d = db * 32 + l31;
      int fv = ((d & 7) ^ ((d >> 3) & 7)) & 7;
#pragma unroll
      for (int ks = 0; ks < 8; ++ks) {
        bf16x8 vv = *reinterpret_cast<const bf16x8*>(
            vbp + (ks >> 2) * 16384 + d * 128 + ((((ks & 3) * 2 + hh) ^ fv) << 4));
        oacc[db] = __builtin_amdgcn_mfma_f32_32x32x16_bf16(pa[ks], vv, oacc[db], 0, 0, 0);
      }
    }
    __builtin_amdgcn_s_setprio(0);

    SB;
    __builtin_amdgcn_s_barrier();          // BAR2: Vs + Ks[cur] reads done
    SB;
  }

  // ---- epilogue: reduce l across halves, normalize, store
  lrow += __shfl_xor(lrow, 32);
  float inv_[16];
#pragma unroll
  for (int r = 0; r < 16; ++r) {
    int qr = (r & 3) + 8 * (r >> 2) + 4 * hh;
    inv_[r] = 1.0f / __shfl(lrow, qr);
  }
#pragma unroll
  for (int db = 0; db < 4; ++db) {
#pragma unroll
    for (int r = 0; r < 16; ++r) {
      int qr = (r & 3) + 8 * (r >> 2) + 4 * hh;
      O[qbase + (size_t)(q0w + qr) * D_DIM + db * 32 + l31] =
          f2bf(oacc[db][r] * inv_[r]);
    }
  }
}

// ---------------- launch ----------------
extern "C" void kernel_launch(void* const* d_in, const int* in_sizes, int n_in,
                              void* d_out, int out_size, void* d_ws, size_t ws_size,
                              hipStream_t stream) {
  const float* x   = (const float*)d_in[0];
  const float* fc  = (const float*)d_in[1];
  const float* fs  = (const float*)d_in[2];
  const float* qw  = (const float*)d_in[3];
  const float* qb  = (const float*)d_in[4];
  const float* kw  = (const float*)d_in[5];
  const float* kb  = (const float*)d_in[6];
  const float* vw  = (const float*)d_in[7];
  const float* vb  = (const float*)d_in[8];
  const float* ow  = (const float*)d_in[9];
  const float* ob  = (const float*)d_in[10];
  const float* qnw = (const float*)d_in[11];
  const float* knw = (const float*)d_in[12];
  float* out = (float*)d_out;

  const size_t MSD = (size_t)MROWS * D_DIM;
  const size_t WSZ = (size_t)D_DIM * D_DIM;
  char* ws = (char*)d_ws;
  unsigned short* xb   = (unsigned short*)ws; ws += MSD * 2;
  unsigned short* qwb  = (unsigned short*)ws; ws += WSZ * 2;   // qwb,kwb,vwb contiguous
  unsigned short* kwb  = (unsigned short*)ws; ws += WSZ * 2;   //   = Bt[6144][2048]
  unsigned short* vwb  = (unsigned short*)ws; ws += WSZ * 2;
  unsigned short* owb  = (unsigned short*)ws; ws += WSZ * 2;
  float*          cbias = (float*)ws;         ws += 3 * D_DIM * 4;
  unsigned short* qpre = (unsigned short*)ws; ws += MSD * 2;   // bf16 pre-norm Q
  unsigned short* kpre = (unsigned short*)ws; ws += MSD * 2;   // bf16 pre-norm K
  unsigned short* qb16 = (unsigned short*)ws; ws += MSD * 2;
  unsigned short* kb16 = (unsigned short*)ws; ws += MSD * 2;   // Kh[b][h][s][d]
  unsigned short* vt16 = (unsigned short*)ws; ws += MSD * 2;   // Vt2[b][h][s/64][d][s%64]
  unsigned short* ob16 = (unsigned short*)ws; ws += MSD * 2;

  cast_all<<<2048, 256, 0, stream>>>(x, qw, kw, vw, ow, xb, qwb, kwb, vwb, owb);
  hipMemcpyAsync(cbias,              qb, D_DIM * sizeof(float), hipMemcpyDeviceToDevice, stream);
  hipMemcpyAsync(cbias + D_DIM,      kb, D_DIM * sizeof(float), hipMemcpyDeviceToDevice, stream);
  hipMemcpyAsync(cbias + 2 * D_DIM,  vb, D_DIM * sizeof(float), hipMemcpyDeviceToDevice, stream);

  // fused QKV projection: M=4096, N=6144, K=2048 -> 384 blocks of 256x256
  gemm256q<<<dim3((MROWS / 256) * (3 * D_DIM / 256)), 512, 0, stream>>>(
      xb, qwb, cbias, qpre, kpre, vt16, MROWS, 3 * D_DIM, D_DIM);

  const float qscale = 0.08838834764831845f * 1.4426950408889634f;
  norm_rope2<<<2 * MROWS, 256, 0, stream>>>(qpre, kpre, qnw, knw, fc, fs,
                                            qb16, kb16, qscale);

  attn_kernel<<<dim3(S_LEN / 256 * NHEAD * B_SZ), 512, 0, stream>>>(qb16, kb16, vt16, ob16);

  // output projection: M=4096, N=2048 -> 512 blocks of 128x128
  gemm_bt<<<dim3((MROWS / 128) * (D_DIM / 128)), 256, 0, stream>>>(
      ob16, owb, ob, out, MROWS, D_DIM, D_DIM);
}

// Round 17
// 292.644 us; speedup vs baseline: 1.0618x; 1.0618x over previous
//
#include <hip/hip_runtime.h>
#include <stdint.h>

#define B_SZ 2
#define S_LEN 2048
#define D_DIM 2048
#define NHEAD 16
#define HD 128
#define HALF 64
#define MROWS (B_SZ * S_LEN)   // 4096

typedef __attribute__((ext_vector_type(8))) __bf16 bf16x8;
typedef __attribute__((ext_vector_type(8))) unsigned short u16x8;
typedef __attribute__((ext_vector_type(4))) float f32x4;
typedef __attribute__((ext_vector_type(16))) float f32x16;
typedef __attribute__((ext_vector_type(4))) unsigned int u32x4;

__device__ inline unsigned short f2bf(float x) {
  union { float f; uint32_t u; } c; c.f = x;
  uint32_t r = (c.u + 0x7fffu + ((c.u >> 16) & 1u)) >> 16;
  return (unsigned short)r;
}

__device__ inline float bf2f(unsigned short b) {
  union { uint32_t u; float f; } c; c.u = (uint32_t)b << 16;
  return c.f;
}

__device__ inline void gll16(const void* g, void* l) {
  __builtin_amdgcn_global_load_lds(
      (const __attribute__((address_space(1))) void*)g,
      (__attribute__((address_space(3))) void*)l,
      16, 0, 0);
}

// ---------------- fused cast f32 -> bf16 for x + 4 weight matrices ----------------
__global__ void cast_all(const float* __restrict__ x,
                         const float* __restrict__ qw, const float* __restrict__ kw,
                         const float* __restrict__ vw, const float* __restrict__ ow,
                         unsigned short* __restrict__ xb,
                         unsigned short* __restrict__ qwb, unsigned short* __restrict__ kwb,
                         unsigned short* __restrict__ vwb, unsigned short* __restrict__ owb) {
  const int n_x = (MROWS * D_DIM) / 4;
  const int n_w = (D_DIM * D_DIM) / 4;      // == 1<<20
  const int total = n_x + 4 * n_w;
  int i = blockIdx.x * blockDim.x + threadIdx.x;
  int stride = gridDim.x * blockDim.x;
  for (; i < total; i += stride) {
    const float* src; unsigned short* dst; int off;
    if (i < n_x) { src = x; dst = xb; off = i; }
    else {
      int j = i - n_x;
      int seg = j >> 20;
      off = j & (n_w - 1);
      src = seg == 0 ? qw : seg == 1 ? kw : seg == 2 ? vw : ow;
      dst = seg == 0 ? qwb : seg == 1 ? kwb : seg == 2 ? vwb : owb;
    }
    float4 v = reinterpret_cast<const float4*>(src)[off];
    ushort4 o;
    o.x = f2bf(v.x); o.y = f2bf(v.y); o.z = f2bf(v.z); o.w = f2bf(v.w);
    reinterpret_cast<ushort4*>(dst)[off] = o;
  }
}

// ---------------- GEMM 128x128 tile, BK=64 + T2 XOR swizzle, 4 waves ----------------
// C[i,j] = sum_k A[i,k]*Bt[j,k] + bias[j].
// BK=64 (halves barrier/vmcnt-drain rounds) + XOR swizzle chunk^=(row&7) on
// BOTH the gll16 global source and the ds_read (0 bank conflicts, round 15).
// LDS 32KB -> 5 blocks/CU. bn-major XCD chunk map (B panels L2-resident per
// XCD; A shared via L3). This measured 831 TF = ~92% of the m97-structure
// ceiling; two attempts at the 256-tile phase template (rounds 11/12, 16)
// both regressed -> keep this structure.
// MODE 0: fp32 linear out -> C0.
// MODE 3: QKV fused (N=6144): seg0 -> (ushort*)C0 bf16 linear, seg1 -> C1 bf16
//         linear, seg2 -> C2 = Vt2[b][h][s/64][d][s%64].
template <int MODE>
__global__ __launch_bounds__(256) void gemm_bt(
    const unsigned short* __restrict__ A, const unsigned short* __restrict__ Bt,
    const float* __restrict__ bias, void* __restrict__ C0,
    unsigned short* __restrict__ C1, unsigned short* __restrict__ C2,
    int M, int N, int K) {
  __shared__ __align__(16) unsigned short As[128 * 64];   // 16KB
  __shared__ __align__(16) unsigned short Bs[128 * 64];   // 16KB
  const int tid = threadIdx.x;
  const int lane = tid & 63;
  const int wave = tid >> 6;
  const int nbn = N >> 7;
  const int xcd = blockIdx.x & 7;
  const int w = blockIdx.x >> 3;        // 0..chunk-1, chunk = 32*(nbn/8)
  const int bm = w & 31;                // M = 4096 -> 32 bm panels
  const int bn = xcd * (nbn >> 3) + (w >> 5);
  const int wr = wave >> 1, wc = wave & 1;
  const int lm = lane & 15, lg = lane >> 4;

  f32x4 acc[4][4] = {};

  for (int k0 = 0; k0 < K; k0 += 64) {
    __syncthreads();
#pragma unroll
    for (int r = 0; r < 4; ++r) {
      int p = r * 4096 + tid * 16;           // byte pos in 16KB tile
      int row = p >> 7;                      // 128B rows (64 bf16)
      int ch = (p >> 4) & 7;                 // 16B chunk in row
      int sc = (ch ^ (row & 7)) << 3;        // pre-swizzled source col (elems)
      gll16(A + (size_t)(bm * 128 + row) * K + k0 + sc, (char*)As + p);
      gll16(Bt + (size_t)(bn * 128 + row) * K + k0 + sc, (char*)Bs + p);
    }
    __syncthreads();

#pragma unroll
    for (int kk = 0; kk < 2; ++kk) {
      bf16x8 af[4], bfr[4];
#pragma unroll
      for (int mi = 0; mi < 4; ++mi) {
        int row = wr * 64 + mi * 16 + lm;
        af[mi] = *reinterpret_cast<const bf16x8*>(
            (const char*)As + row * 128 + ((((kk << 2) + lg) ^ (row & 7)) << 4));
      }
#pragma unroll
      for (int ni = 0; ni < 4; ++ni) {
        int row = wc * 64 + ni * 16 + lm;
        bfr[ni] = *reinterpret_cast<const bf16x8*>(
            (const char*)Bs + row * 128 + ((((kk << 2) + lg) ^ (row & 7)) << 4));
      }
#pragma unroll
      for (int mi = 0; mi < 4; ++mi)
#pragma unroll
        for (int ni = 0; ni < 4; ++ni)
          acc[mi][ni] = __builtin_amdgcn_mfma_f32_16x16x32_bf16(
              af[mi], bfr[ni], acc[mi][ni], 0, 0, 0);
    }
  }

#pragma unroll
  for (int ni = 0; ni < 4; ++ni) {
    int col = bn * 128 + wc * 64 + ni * 16 + lm;
    float bv = bias[col];
    if constexpr (MODE == 3) {
      int seg = col >> 11;            // 0=Q, 1=K, 2=V
      int c2 = col & (D_DIM - 1);
#pragma unroll
      for (int mi = 0; mi < 4; ++mi) {
        int row0 = bm * 128 + wr * 64 + mi * 16 + lg * 4;
        if (seg == 2) {
          int b = row0 >> 11, s0 = row0 & (S_LEN - 1);
          int h = c2 >> 7, d = c2 & (HD - 1);
          ushort4 o;
          o.x = f2bf(acc[mi][ni][0] + bv);
          o.y = f2bf(acc[mi][ni][1] + bv);
          o.z = f2bf(acc[mi][ni][2] + bv);
          o.w = f2bf(acc[mi][ni][3] + bv);
          size_t oi = ((((size_t)(b * NHEAD + h) * (S_LEN / 64) + (s0 >> 6)) * HD + d) << 6)
                      + (s0 & 63);
          *reinterpret_cast<ushort4*>(C2 + oi) = o;
        } else {
          unsigned short* dst = (seg == 0) ? (unsigned short*)C0 : C1;
#pragma unroll
          for (int r = 0; r < 4; ++r)
            dst[(size_t)(row0 + r) * D_DIM + c2] = f2bf(acc[mi][ni][r] + bv);
        }
      }
    } else {
      float* out = (float*)C0;
#pragma unroll
      for (int mi = 0; mi < 4; ++mi) {
        int row0 = bm * 128 + wr * 64 + mi * 16 + lg * 4;
#pragma unroll
        for (int r = 0; r < 4; ++r)
          out[(size_t)(row0 + r) * N + col] = acc[mi][ni][r] + bv;
      }
    }
  }
}

// ---------------- merged RMSNorm+RoPE for Q (linear out) and K (head-blocked out) ----------------
__global__ __launch_bounds__(256) void norm_rope2(
    const unsigned short* __restrict__ qin, const unsigned short* __restrict__ kin,
    const float* __restrict__ qnw, const float* __restrict__ knw,
    const float* __restrict__ cosb, const float* __restrict__ sinb,
    unsigned short* __restrict__ qout, unsigned short* __restrict__ kout,
    float qscale) {
  const int isK = blockIdx.x >> 12;                // grid = 2*MROWS
  const int row = blockIdx.x & (MROWS - 1);
  const int pos = row & (S_LEN - 1);
  const unsigned short* hr = (isK ? kin : qin) + (size_t)row * D_DIM;
  const float* w = isK ? knw : qnw;
  const float outscale = isK ? 1.0f : qscale;
  const int t = threadIdx.x;
  const int d = t * 8;

  u16x8 hv = *reinterpret_cast<const u16x8*>(hr + d);
  float a[8];
#pragma unroll
  for (int i = 0; i < 8; ++i) a[i] = bf2f(hv[i]);
  float ss = 0.f;
#pragma unroll
  for (int i = 0; i < 8; ++i) ss += a[i] * a[i];
#pragma unroll
  for (int off = 32; off > 0; off >>= 1) ss += __shfl_down(ss, off);
  __shared__ float red[4];
  if ((t & 63) == 0) red[t >> 6] = ss;
  __syncthreads();
  float tot = red[0] + red[1] + red[2] + red[3];
  float inv = rsqrtf(tot * (1.0f / D_DIM) + 1e-6f) * outscale;

  const int p = (d & (HD - 1)) >> 1;
  const float* cp = cosb + pos * HALF + p;
  const float* sp = sinb + pos * HALF + p;
  const float* wp = w + d;

  float c0 = cp[0], c1 = cp[1], c2 = cp[2], c3 = cp[3];
  float s0 = sp[0], s1 = sp[1], s2 = sp[2], s3 = sp[3];
#pragma unroll
  for (int i = 0; i < 8; ++i) a[i] = a[i] * inv * wp[i];
  u16x8 o;
  o[0] = f2bf(a[0] * c0 - a[1] * s0);
  o[1] = f2bf(a[0] * s0 + a[1] * c0);
  o[2] = f2bf(a[2] * c1 - a[3] * s1);
  o[3] = f2bf(a[2] * s1 + a[3] * c1);
  o[4] = f2bf(a[4] * c2 - a[5] * s2);
  o[5] = f2bf(a[4] * s2 + a[5] * c2);
  o[6] = f2bf(a[6] * c3 - a[7] * s3);
  o[7] = f2bf(a[6] * s3 + a[7] * c3);
  if (isK) {
    int hh = t >> 4;
    int dd = d & (HD - 1);
    size_t oi = (((size_t)((row >> 11) * NHEAD + hh) * S_LEN) + pos) * HD + dd;
    *reinterpret_cast<u16x8*>(kout + oi) = o;
  } else {
    *reinterpret_cast<u16x8*>(qout + (size_t)row * D_DIM + d) = o;
  }
}

// ---------------- flash attention: 8 waves x 32q (QBLK=256), KVBLK=128 ----------------
__global__ __launch_bounds__(512) void attn_kernel(
    const unsigned short* __restrict__ Q, const unsigned short* __restrict__ Kh,
    const unsigned short* __restrict__ Vt, unsigned short* __restrict__ O) {
  const int idx = blockIdx.x;
  const int swz = (idx & 7) * 32 + (idx >> 3);   // 256 blocks, 32/XCD (4 heads)
  const int qb = swz & 7;
  const int h = (swz >> 3) & 15;
  const int b = swz >> 7;

  const int tid = threadIdx.x;
  const int lane = tid & 63;
  const int wave = tid >> 6;          // 0..7
  const int l31 = lane & 31;
  const int hh = lane >> 5;

  const size_t qbase = (size_t)b * S_LEN * D_DIM + (size_t)h * HD;   // linear Q/O
  const size_t hbase = (size_t)(b * NHEAD + h) * S_LEN * HD;         // blocked K/V
  const int q0w = qb * 256 + wave * 32;

  __shared__ __align__(16) unsigned short Ks[2 * 128 * 128];  // 2 x 32KB (dbuf)
  __shared__ __align__(16) unsigned short Vs[2 * 128 * 64];   // 32KB (2 s-halves)

  bf16x8 qf[8];
#pragma unroll
  for (int ds_ = 0; ds_ < 8; ++ds_)
    qf[ds_] = *reinterpret_cast<const bf16x8*>(
        Q + qbase + (size_t)(q0w + l31) * D_DIM + ds_ * 16 + hh * 8);

  f32x16 oacc[4] = {};
  float mrow = -1e30f, lrow = 0.f;

  const int pbase = wave * 1024 + (lane << 4);   // + j*8192, j=0..3 -> [0,32768)

  auto stageK = [&](int buf, int tix) {
    const unsigned short* ksrc = Kh + hbase + (size_t)tix * (128 * HD);
#pragma unroll
    for (int j = 0; j < 4; ++j) {
      int p = pbase + j * 8192;
      int kr = p >> 8;                                   // row 0..127 (256B rows)
      int kc = ((p >> 4) & 15) ^ ((kr & 7) ^ ((kr >> 3) & 7));
      gll16(ksrc + kr * 128 + kc * 8, (char*)Ks + buf * 32768 + p);
    }
  };
  auto stageV = [&](int tix) {
    const unsigned short* vsrc = Vt + hbase + (size_t)tix * (128 * HD);  // 2 v-tiles
#pragma unroll
    for (int j = 0; j < 4; ++j) {
      int p = pbase + j * 8192;
      int vr = (p & 16383) >> 7;                         // d-row 0..127 (128B rows)
      int vc = ((p >> 4) & 7) ^ (((vr & 7) ^ ((vr >> 3) & 7)) & 7);
      gll16(vsrc + (p >> 14) * (64 * HD) + vr * 64 + vc * 8, (char*)Vs + p);
    }
  };

  stageK(0, 0);   // 4 K-loads in flight

  const int NT = S_LEN / 128;          // 16
  for (int t = 0; t < NT; ++t) {
    const int cur = t & 1;
    stageV(t);                                          // +4 (V(t))
    stageK(cur ^ 1, (t + 1 < NT) ? t + 1 : t);          // +4 (K(t+1))
    asm volatile("s_waitcnt vmcnt(8)" ::: "memory");    // drain K(t) (oldest 4)
    __builtin_amdgcn_sched_barrier(0);
    __builtin_amdgcn_s_barrier();          // BAR1: K(t) visible
    __builtin_amdgcn_sched_barrier(0);

    // ---- QK^T swapped: sc[j] = P[k = 32j..32j+31][q = l31]
    const char* kbp = (const char*)Ks + cur * 32768;
    f32x16 sc[4] = {};
    __builtin_amdgcn_s_setprio(1);
#pragma unroll
    for (int ds_ = 0; ds_ < 8; ++ds_) {
#pragma unroll
      for (int j = 0; j < 4; ++j) {
        int r = j * 32 + l31;
        bf16x8 kf = *reinterpret_cast<const bf16x8*>(
            kbp + r * 256 + (((ds_ * 2 + hh) ^ ((r & 7) ^ ((r >> 3) & 7))) << 4));
        sc[j] = __builtin_amdgcn_mfma_f32_32x32x16_bf16(kf, qf[ds_], sc[j], 0, 0, 0);
      }
    }
    __builtin_amdgcn_s_setprio(0);

    // ---- online softmax (per-lane q-row = l31), tree reductions over 64 vals
    float m0[16];
#pragma unroll
    for (int r = 0; r < 16; ++r)
      m0[r] = fmaxf(fmaxf(sc[0][r], sc[1][r]), fmaxf(sc[2][r], sc[3][r]));
#pragma unroll
    for (int r = 0; r < 8; ++r) m0[r] = fmaxf(m0[r], m0[r + 8]);
#pragma unroll
    for (int r = 0; r < 4; ++r) m0[r] = fmaxf(m0[r], m0[r + 4]);
    float mx = fmaxf(fmaxf(m0[0], m0[1]), fmaxf(m0[2], m0[3]));
    mx = fmaxf(mx, __shfl_xor(mx, 32));
    if (__any(mx > mrow + 8.0f)) {          // defer-max rescale (rare)
      float nm = fmaxf(mrow, mx);
      float alpha = exp2f(mrow - nm);
      mrow = nm;
      lrow *= alpha;
#pragma unroll
      for (int r = 0; r < 16; ++r) {
        int qr = (r & 3) + 8 * (r >> 2) + 4 * hh;
        float av = __shfl(alpha, qr);
        oacc[0][r] *= av; oacc[1][r] *= av; oacc[2][r] *= av; oacc[3][r] *= av;
      }
    }
#pragma unroll
    for (int j = 0; j < 4; ++j)
#pragma unroll
      for (int r = 0; r < 16; ++r) sc[j][r] = exp2f(sc[j][r] - mrow);
    float s0[16];
#pragma unroll
    for (int r = 0; r < 16; ++r)
      s0[r] = (sc[0][r] + sc[1][r]) + (sc[2][r] + sc[3][r]);
#pragma unroll
    for (int r = 0; r < 8; ++r) s0[r] += s0[r + 8];
#pragma unroll
    for (int r = 0; r < 4; ++r) s0[r] += s0[r + 4];
    lrow += (s0[0] + s0[1]) + (s0[2] + s0[3]);

    // ---- P -> bf16 A-frags in-register (cvt_pk + permlane32_swap)
    uint32_t w[32];
#pragma unroll
    for (int X = 0; X < 4; ++X) {
#pragma unroll
      for (int g = 0; g < 4; ++g) {
        uint32_t lo, hi;
        float a0 = sc[X][4 * g], a1 = sc[X][4 * g + 1];
        float a2 = sc[X][4 * g + 2], a3 = sc[X][4 * g + 3];
        asm("v_cvt_pk_bf16_f32 %0, %1, %2" : "=v"(lo) : "v"(a0), "v"(a1));
        asm("v_cvt_pk_bf16_f32 %0, %1, %2" : "=v"(hi) : "v"(a2), "v"(a3));
        w[X * 8 + g * 2] = lo; w[X * 8 + g * 2 + 1] = hi;
      }
    }
    bf16x8 pa[8];
#pragma unroll
    for (int s = 0; s < 8; ++s) {
      int wb = (s >> 1) * 8 + (s & 1) * 4;
      uint32_t le = w[wb], he = w[wb + 1], lo_ = w[wb + 2], ho = w[wb + 3];
      asm("v_permlane32_swap_b32 %0, %1" : "+v"(le), "+v"(lo_));
      asm("v_permlane32_swap_b32 %0, %1" : "+v"(he), "+v"(ho));
      u32x4 fr = {le, he, lo_, ho};
      pa[s] = __builtin_bit_cast(bf16x8, fr);
    }

    // ---- wait V(t) (drains to 4: K(t+1) stays in flight), then barrier
    asm volatile("s_waitcnt vmcnt(4)" ::: "memory");
    __builtin_amdgcn_sched_barrier(0);
    __builtin_amdgcn_s_barrier();          // BAR-mid: V(t) visible
    __builtin_amdgcn_sched_barrier(0);

    // ---- PV: O[q][d] += P[q][k] V[k][d], k 0..127 in 8 slots
    const char* vbp = (const char*)Vs;
    __builtin_amdgcn_s_setprio(1);
#pragma unroll
    for (int db = 0; db < 4; ++db) {
      int d = db * 32 + l31;
      int fv = ((d & 7) ^ ((d >> 3) & 7)) & 7;
#pragma unroll
      for (int ks = 0; ks < 8; ++ks) {
        bf16x8 vv = *reinterpret_cast<const bf16x8*>(
            vbp + (ks >> 2) * 16384 + d * 128 + ((((ks & 3) * 2 + hh) ^ fv) << 4));
        oacc[db] = __builtin_amdgcn_mfma_f32_32x32x16_bf16(pa[ks], vv, oacc[db], 0, 0, 0);
      }
    }
    __builtin_amdgcn_s_setprio(0);

    __builtin_amdgcn_sched_barrier(0);
    __builtin_amdgcn_s_barrier();          // BAR2: Vs + Ks[cur] reads done
    __builtin_amdgcn_sched_barrier(0);
  }

  // ---- epilogue: reduce l across halves, normalize, store
  lrow += __shfl_xor(lrow, 32);
  float inv_[16];
#pragma unroll
  for (int r = 0; r < 16; ++r) {
    int qr = (r & 3) + 8 * (r >> 2) + 4 * hh;
    inv_[r] = 1.0f / __shfl(lrow, qr);
  }
#pragma unroll
  for (int db = 0; db < 4; ++db) {
#pragma unroll
    for (int r = 0; r < 16; ++r) {
      int qr = (r & 3) + 8 * (r >> 2) + 4 * hh;
      O[qbase + (size_t)(q0w + qr) * D_DIM + db * 32 + l31] =
          f2bf(oacc[db][r] * inv_[r]);
    }
  }
}

// ---------------- launch ----------------
extern "C" void kernel_launch(void* const* d_in, const int* in_sizes, int n_in,
                              void* d_out, int out_size, void* d_ws, size_t ws_size,
                              hipStream_t stream) {
  const float* x   = (const float*)d_in[0];
  const float* fc  = (const float*)d_in[1];
  const float* fs  = (const float*)d_in[2];
  const float* qw  = (const float*)d_in[3];
  const float* qb  = (const float*)d_in[4];
  const float* kw  = (const float*)d_in[5];
  const float* kb  = (const float*)d_in[6];
  const float* vw  = (const float*)d_in[7];
  const float* vb  = (const float*)d_in[8];
  const float* ow  = (const float*)d_in[9];
  const float* ob  = (const float*)d_in[10];
  const float* qnw = (const float*)d_in[11];
  const float* knw = (const float*)d_in[12];
  float* out = (float*)d_out;

  const size_t MSD = (size_t)MROWS * D_DIM;
  const size_t WSZ = (size_t)D_DIM * D_DIM;
  char* ws = (char*)d_ws;
  unsigned short* xb   = (unsigned short*)ws; ws += MSD * 2;
  unsigned short* qwb  = (unsigned short*)ws; ws += WSZ * 2;   // qwb,kwb,vwb contiguous
  unsigned short* kwb  = (unsigned short*)ws; ws += WSZ * 2;   //   = Bt[6144][2048]
  unsigned short* vwb  = (unsigned short*)ws; ws += WSZ * 2;
  unsigned short* owb  = (unsigned short*)ws; ws += WSZ * 2;
  float*          cbias = (float*)ws;         ws += 3 * D_DIM * 4;
  unsigned short* qpre = (unsigned short*)ws; ws += MSD * 2;   // bf16 pre-norm Q
  unsigned short* kpre = (unsigned short*)ws; ws += MSD * 2;   // bf16 pre-norm K
  unsigned short* qb16 = (unsigned short*)ws; ws += MSD * 2;
  unsigned short* kb16 = (unsigned short*)ws; ws += MSD * 2;   // Kh[b][h][s][d]
  unsigned short* vt16 = (unsigned short*)ws; ws += MSD * 2;   // Vt2[b][h][s/64][d][s%64]
  unsigned short* ob16 = (unsigned short*)ws; ws += MSD * 2;

  cast_all<<<2048, 256, 0, stream>>>(x, qw, kw, vw, ow, xb, qwb, kwb, vwb, owb);
  hipMemcpyAsync(cbias,              qb, D_DIM * sizeof(float), hipMemcpyDeviceToDevice, stream);
  hipMemcpyAsync(cbias + D_DIM,      kb, D_DIM * sizeof(float), hipMemcpyDeviceToDevice, stream);
  hipMemcpyAsync(cbias + 2 * D_DIM,  vb, D_DIM * sizeof(float), hipMemcpyDeviceToDevice, stream);

  // fused QKV projection: M=4096, N=6144, K=2048 -> 1536 blocks (~5/CU)
  gemm_bt<3><<<dim3((MROWS / 128) * (3 * D_DIM / 128)), 256, 0, stream>>>(
      xb, qwb, cbias, qpre, kpre, vt16, MROWS, 3 * D_DIM, D_DIM);

  const float qscale = 0.08838834764831845f * 1.4426950408889634f;
  norm_rope2<<<2 * MROWS, 256, 0, stream>>>(qpre, kpre, qnw, knw, fc, fs,
                                            qb16, kb16, qscale);

  attn_kernel<<<dim3(S_LEN / 256 * NHEAD * B_SZ), 512, 0, stream>>>(qb16, kb16, vt16, ob16);

  // output projection: M=4096, N=2048 -> 512 blocks
  gemm_bt<0><<<dim3((MROWS / 128) * (D_DIM / 128)), 256, 0, stream>>>(
      ob16, owb, ob, out, nullptr, nullptr, MROWS, D_DIM, D_DIM);
}

// Round 18
// 286.067 us; speedup vs baseline: 1.0862x; 1.0230x over previous
//
#include <hip/hip_runtime.h>
#include <stdint.h>

#define B_SZ 2
#define S_LEN 2048
#define D_DIM 2048
#define NHEAD 16
#define HD 128
#define HALF 64
#define MROWS (B_SZ * S_LEN)   // 4096

typedef __attribute__((ext_vector_type(8))) __bf16 bf16x8;
typedef __attribute__((ext_vector_type(8))) unsigned short u16x8;
typedef __attribute__((ext_vector_type(4))) float f32x4;
typedef __attribute__((ext_vector_type(16))) float f32x16;
typedef __attribute__((ext_vector_type(4))) unsigned int u32x4;

__device__ inline unsigned short f2bf(float x) {
  union { float f; uint32_t u; } c; c.f = x;
  uint32_t r = (c.u + 0x7fffu + ((c.u >> 16) & 1u)) >> 16;
  return (unsigned short)r;
}

__device__ inline float bf2f(unsigned short b) {
  union { uint32_t u; float f; } c; c.u = (uint32_t)b << 16;
  return c.f;
}

__device__ inline void gll16(const void* g, void* l) {
  __builtin_amdgcn_global_load_lds(
      (const __attribute__((address_space(1))) void*)g,
      (__attribute__((address_space(3))) void*)l,
      16, 0, 0);
}

// ---------------- fused cast f32 -> bf16 for x + 4 weight matrices ----------------
__global__ void cast_all(const float* __restrict__ x,
                         const float* __restrict__ qw, const float* __restrict__ kw,
                         const float* __restrict__ vw, const float* __restrict__ ow,
                         unsigned short* __restrict__ xb,
                         unsigned short* __restrict__ qwb, unsigned short* __restrict__ kwb,
                         unsigned short* __restrict__ vwb, unsigned short* __restrict__ owb) {
  const int n_x = (MROWS * D_DIM) / 4;
  const int n_w = (D_DIM * D_DIM) / 4;      // == 1<<20
  const int total = n_x + 4 * n_w;
  int i = blockIdx.x * blockDim.x + threadIdx.x;
  int stride = gridDim.x * blockDim.x;
  for (; i < total; i += stride) {
    const float* src; unsigned short* dst; int off;
    if (i < n_x) { src = x; dst = xb; off = i; }
    else {
      int j = i - n_x;
      int seg = j >> 20;
      off = j & (n_w - 1);
      src = seg == 0 ? qw : seg == 1 ? kw : seg == 2 ? vw : ow;
      dst = seg == 0 ? qwb : seg == 1 ? kwb : seg == 2 ? vwb : owb;
    }
    float4 v = reinterpret_cast<const float4*>(src)[off];
    ushort4 o;
    o.x = f2bf(v.x); o.y = f2bf(v.y); o.z = f2bf(v.z); o.w = f2bf(v.w);
    reinterpret_cast<ushort4*>(dst)[off] = o;
  }
}

// ---------------- GEMM 128x128 tile, BK=64 + T2 XOR swizzle, 4 waves ----------------
// C[i,j] = sum_k A[i,k]*Bt[j,k] + bias[j].
// BK=64 (halves barrier/vmcnt-drain rounds) + XOR swizzle chunk^=(row&7) on
// BOTH the gll16 global source and the ds_read (0 bank conflicts, round 15).
// LDS 32KB -> 5 blocks/CU. bn-major XCD chunk map (B panels L2-resident per
// XCD; A shared via L3). Measured 831 TF = ~92% of the m97-structure ceiling;
// two attempts at the 256-tile phase template (rounds 11/12, 16) regressed.
// MODE 0: fp32 linear out -> C0 (bias = b0).
// MODE 3: QKV fused (N=6144): seg0 -> (ushort*)C0 bf16 linear (bias b0),
//         seg1 -> C1 bf16 linear (bias b1),
//         seg2 -> C2 = Vt2[b][h][s/64][d][s%64] (bias b2).
template <int MODE>
__global__ __launch_bounds__(256) void gemm_bt(
    const unsigned short* __restrict__ A, const unsigned short* __restrict__ Bt,
    const float* __restrict__ b0, const float* __restrict__ b1,
    const float* __restrict__ b2, void* __restrict__ C0,
    unsigned short* __restrict__ C1, unsigned short* __restrict__ C2,
    int M, int N, int K) {
  __shared__ __align__(16) unsigned short As[128 * 64];   // 16KB
  __shared__ __align__(16) unsigned short Bs[128 * 64];   // 16KB
  const int tid = threadIdx.x;
  const int lane = tid & 63;
  const int wave = tid >> 6;
  const int nbn = N >> 7;
  const int xcd = blockIdx.x & 7;
  const int w = blockIdx.x >> 3;        // 0..chunk-1, chunk = 32*(nbn/8)
  const int bm = w & 31;                // M = 4096 -> 32 bm panels
  const int bn = xcd * (nbn >> 3) + (w >> 5);
  const int wr = wave >> 1, wc = wave & 1;
  const int lm = lane & 15, lg = lane >> 4;

  f32x4 acc[4][4] = {};

  for (int k0 = 0; k0 < K; k0 += 64) {
    __syncthreads();
#pragma unroll
    for (int r = 0; r < 4; ++r) {
      int p = r * 4096 + tid * 16;           // byte pos in 16KB tile
      int row = p >> 7;                      // 128B rows (64 bf16)
      int ch = (p >> 4) & 7;                 // 16B chunk in row
      int sc = (ch ^ (row & 7)) << 3;        // pre-swizzled source col (elems)
      gll16(A + (size_t)(bm * 128 + row) * K + k0 + sc, (char*)As + p);
      gll16(Bt + (size_t)(bn * 128 + row) * K + k0 + sc, (char*)Bs + p);
    }
    __syncthreads();

#pragma unroll
    for (int kk = 0; kk < 2; ++kk) {
      bf16x8 af[4], bfr[4];
#pragma unroll
      for (int mi = 0; mi < 4; ++mi) {
        int row = wr * 64 + mi * 16 + lm;
        af[mi] = *reinterpret_cast<const bf16x8*>(
            (const char*)As + row * 128 + ((((kk << 2) + lg) ^ (row & 7)) << 4));
      }
#pragma unroll
      for (int ni = 0; ni < 4; ++ni) {
        int row = wc * 64 + ni * 16 + lm;
        bfr[ni] = *reinterpret_cast<const bf16x8*>(
            (const char*)Bs + row * 128 + ((((kk << 2) + lg) ^ (row & 7)) << 4));
      }
#pragma unroll
      for (int mi = 0; mi < 4; ++mi)
#pragma unroll
        for (int ni = 0; ni < 4; ++ni)
          acc[mi][ni] = __builtin_amdgcn_mfma_f32_16x16x32_bf16(
              af[mi], bfr[ni], acc[mi][ni], 0, 0, 0);
    }
  }

#pragma unroll
  for (int ni = 0; ni < 4; ++ni) {
    int col = bn * 128 + wc * 64 + ni * 16 + lm;
    if constexpr (MODE == 3) {
      int seg = col >> 11;            // 0=Q, 1=K, 2=V
      int c2 = col & (D_DIM - 1);
      float bv = (seg == 0 ? b0 : seg == 1 ? b1 : b2)[c2];
#pragma unroll
      for (int mi = 0; mi < 4; ++mi) {
        int row0 = bm * 128 + wr * 64 + mi * 16 + lg * 4;
        if (seg == 2) {
          int b = row0 >> 11, s0 = row0 & (S_LEN - 1);
          int h = c2 >> 7, d = c2 & (HD - 1);
          ushort4 o;
          o.x = f2bf(acc[mi][ni][0] + bv);
          o.y = f2bf(acc[mi][ni][1] + bv);
          o.z = f2bf(acc[mi][ni][2] + bv);
          o.w = f2bf(acc[mi][ni][3] + bv);
          size_t oi = ((((size_t)(b * NHEAD + h) * (S_LEN / 64) + (s0 >> 6)) * HD + d) << 6)
                      + (s0 & 63);
          *reinterpret_cast<ushort4*>(C2 + oi) = o;
        } else {
          unsigned short* dst = (seg == 0) ? (unsigned short*)C0 : C1;
#pragma unroll
          for (int r = 0; r < 4; ++r)
            dst[(size_t)(row0 + r) * D_DIM + c2] = f2bf(acc[mi][ni][r] + bv);
        }
      }
    } else {
      float bv = b0[col];
      float* out = (float*)C0;
#pragma unroll
      for (int mi = 0; mi < 4; ++mi) {
        int row0 = bm * 128 + wr * 64 + mi * 16 + lg * 4;
#pragma unroll
        for (int r = 0; r < 4; ++r)
          out[(size_t)(row0 + r) * N + col] = acc[mi][ni][r] + bv;
      }
    }
  }
}

// ---------------- merged RMSNorm+RoPE for Q (linear out) and K (head-blocked out) ----------------
__global__ __launch_bounds__(256) void norm_rope2(
    const unsigned short* __restrict__ qin, const unsigned short* __restrict__ kin,
    const float* __restrict__ qnw, const float* __restrict__ knw,
    const float* __restrict__ cosb, const float* __restrict__ sinb,
    unsigned short* __restrict__ qout, unsigned short* __restrict__ kout,
    float qscale) {
  const int isK = blockIdx.x >> 12;                // grid = 2*MROWS
  const int row = blockIdx.x & (MROWS - 1);
  const int pos = row & (S_LEN - 1);
  const unsigned short* hr = (isK ? kin : qin) + (size_t)row * D_DIM;
  const float* w = isK ? knw : qnw;
  const float outscale = isK ? 1.0f : qscale;
  const int t = threadIdx.x;
  const int d = t * 8;

  u16x8 hv = *reinterpret_cast<const u16x8*>(hr + d);
  float a[8];
#pragma unroll
  for (int i = 0; i < 8; ++i) a[i] = bf2f(hv[i]);
  float ss = 0.f;
#pragma unroll
  for (int i = 0; i < 8; ++i) ss += a[i] * a[i];
#pragma unroll
  for (int off = 32; off > 0; off >>= 1) ss += __shfl_down(ss, off);
  __shared__ float red[4];
  if ((t & 63) == 0) red[t >> 6] = ss;
  __syncthreads();
  float tot = red[0] + red[1] + red[2] + red[3];
  float inv = rsqrtf(tot * (1.0f / D_DIM) + 1e-6f) * outscale;

  const int p = (d & (HD - 1)) >> 1;
  const float* cp = cosb + pos * HALF + p;
  const float* sp = sinb + pos * HALF + p;
  const float* wp = w + d;

  float c0 = cp[0], c1 = cp[1], c2 = cp[2], c3 = cp[3];
  float s0 = sp[0], s1 = sp[1], s2 = sp[2], s3 = sp[3];
#pragma unroll
  for (int i = 0; i < 8; ++i) a[i] = a[i] * inv * wp[i];
  u16x8 o;
  o[0] = f2bf(a[0] * c0 - a[1] * s0);
  o[1] = f2bf(a[0] * s0 + a[1] * c0);
  o[2] = f2bf(a[2] * c1 - a[3] * s1);
  o[3] = f2bf(a[2] * s1 + a[3] * c1);
  o[4] = f2bf(a[4] * c2 - a[5] * s2);
  o[5] = f2bf(a[4] * s2 + a[5] * c2);
  o[6] = f2bf(a[6] * c3 - a[7] * s3);
  o[7] = f2bf(a[6] * s3 + a[7] * c3);
  if (isK) {
    int hh = t >> 4;
    int dd = d & (HD - 1);
    size_t oi = (((size_t)((row >> 11) * NHEAD + hh) * S_LEN) + pos) * HD + dd;
    *reinterpret_cast<u16x8*>(kout + oi) = o;
  } else {
    *reinterpret_cast<u16x8*>(qout + (size_t)row * D_DIM + d) = o;
  }
}

// ---------------- flash attention: 8 waves x 32q (QBLK=256), KVBLK=128 ----------------
__global__ __launch_bounds__(512) void attn_kernel(
    const unsigned short* __restrict__ Q, const unsigned short* __restrict__ Kh,
    const unsigned short* __restrict__ Vt, unsigned short* __restrict__ O) {
  const int idx = blockIdx.x;
  const int swz = (idx & 7) * 32 + (idx >> 3);   // 256 blocks, 32/XCD (4 heads)
  const int qb = swz & 7;
  const int h = (swz >> 3) & 15;
  const int b = swz >> 7;

  const int tid = threadIdx.x;
  const int lane = tid & 63;
  const int wave = tid >> 6;          // 0..7
  const int l31 = lane & 31;
  const int hh = lane >> 5;

  const size_t qbase = (size_t)b * S_LEN * D_DIM + (size_t)h * HD;   // linear Q/O
  const size_t hbase = (size_t)(b * NHEAD + h) * S_LEN * HD;         // blocked K/V
  const int q0w = qb * 256 + wave * 32;

  __shared__ __align__(16) unsigned short Ks[2 * 128 * 128];  // 2 x 32KB (dbuf)
  __shared__ __align__(16) unsigned short Vs[2 * 128 * 64];   // 32KB (2 s-halves)

  bf16x8 qf[8];
#pragma unroll
  for (int ds_ = 0; ds_ < 8; ++ds_)
    qf[ds_] = *reinterpret_cast<const bf16x8*>(
        Q + qbase + (size_t)(q0w + l31) * D_DIM + ds_ * 16 + hh * 8);

  f32x16 oacc[4] = {};
  float mrow = -1e30f, lrow = 0.f;

  const int pbase = wave * 1024 + (lane << 4);   // + j*8192, j=0..3 -> [0,32768)

  auto stageK = [&](int buf, int tix) {
    const unsigned short* ksrc = Kh + hbase + (size_t)tix * (128 * HD);
#pragma unroll
    for (int j = 0; j < 4; ++j) {
      int p = pbase + j * 8192;
      int kr = p >> 8;                                   // row 0..127 (256B rows)
      int kc = ((p >> 4) & 15) ^ ((kr & 7) ^ ((kr >> 3) & 7));
      gll16(ksrc + kr * 128 + kc * 8, (char*)Ks + buf * 32768 + p);
    }
  };
  auto stageV = [&](int tix) {
    const unsigned short* vsrc = Vt + hbase + (size_t)tix * (128 * HD);  // 2 v-tiles
#pragma unroll
    for (int j = 0; j < 4; ++j) {
      int p = pbase + j * 8192;
      int vr = (p & 16383) >> 7;                         // d-row 0..127 (128B rows)
      int vc = ((p >> 4) & 7) ^ (((vr & 7) ^ ((vr >> 3) & 7)) & 7);
      gll16(vsrc + (p >> 14) * (64 * HD) + vr * 64 + vc * 8, (char*)Vs + p);
    }
  };

  stageK(0, 0);   // 4 K-loads in flight

  const int NT = S_LEN / 128;          // 16
  for (int t = 0; t < NT; ++t) {
    const int cur = t & 1;
    stageV(t);                                          // +4 (V(t))
    stageK(cur ^ 1, (t + 1 < NT) ? t + 1 : t);          // +4 (K(t+1))
    asm volatile("s_waitcnt vmcnt(8)" ::: "memory");    // drain K(t) (oldest 4)
    __builtin_amdgcn_sched_barrier(0);
    __builtin_amdgcn_s_barrier();          // BAR1: K(t) visible
    __builtin_amdgcn_sched_barrier(0);

    // ---- QK^T swapped: sc[j] = P[k = 32j..32j+31][q = l31]
    const char* kbp = (const char*)Ks + cur * 32768;
    f32x16 sc[4] = {};
    __builtin_amdgcn_s_setprio(1);
#pragma unroll
    for (int ds_ = 0; ds_ < 8; ++ds_) {
#pragma unroll
      for (int j = 0; j < 4; ++j) {
        int r = j * 32 + l31;
        bf16x8 kf = *reinterpret_cast<const bf16x8*>(
            kbp + r * 256 + (((ds_ * 2 + hh) ^ ((r & 7) ^ ((r >> 3) & 7))) << 4));
        sc[j] = __builtin_amdgcn_mfma_f32_32x32x16_bf16(kf, qf[ds_], sc[j], 0, 0, 0);
      }
    }
    __builtin_amdgcn_s_setprio(0);

    // ---- online softmax (per-lane q-row = l31), tree reductions over 64 vals
    float m0[16];
#pragma unroll
    for (int r = 0; r < 16; ++r)
      m0[r] = fmaxf(fmaxf(sc[0][r], sc[1][r]), fmaxf(sc[2][r], sc[3][r]));
#pragma unroll
    for (int r = 0; r < 8; ++r) m0[r] = fmaxf(m0[r], m0[r + 8]);
#pragma unroll
    for (int r = 0; r < 4; ++r) m0[r] = fmaxf(m0[r], m0[r + 4]);
    float mx = fmaxf(fmaxf(m0[0], m0[1]), fmaxf(m0[2], m0[3]));
    mx = fmaxf(mx, __shfl_xor(mx, 32));
    if (__any(mx > mrow + 8.0f)) {          // defer-max rescale (rare)
      float nm = fmaxf(mrow, mx);
      float alpha = exp2f(mrow - nm);
      mrow = nm;
      lrow *= alpha;
#pragma unroll
      for (int r = 0; r < 16; ++r) {
        int qr = (r & 3) + 8 * (r >> 2) + 4 * hh;
        float av = __shfl(alpha, qr);
        oacc[0][r] *= av; oacc[1][r] *= av; oacc[2][r] *= av; oacc[3][r] *= av;
      }
    }
#pragma unroll
    for (int j = 0; j < 4; ++j)
#pragma unroll
      for (int r = 0; r < 16; ++r) sc[j][r] = exp2f(sc[j][r] - mrow);
    float s0[16];
#pragma unroll
    for (int r = 0; r < 16; ++r)
      s0[r] = (sc[0][r] + sc[1][r]) + (sc[2][r] + sc[3][r]);
#pragma unroll
    for (int r = 0; r < 8; ++r) s0[r] += s0[r + 8];
#pragma unroll
    for (int r = 0; r < 4; ++r) s0[r] += s0[r + 4];
    lrow += (s0[0] + s0[1]) + (s0[2] + s0[3]);

    // ---- P -> bf16 A-frags in-register (cvt_pk + permlane32_swap)
    uint32_t w[32];
#pragma unroll
    for (int X = 0; X < 4; ++X) {
#pragma unroll
      for (int g = 0; g < 4; ++g) {
        uint32_t lo, hi;
        float a0 = sc[X][4 * g], a1 = sc[X][4 * g + 1];
        float a2 = sc[X][4 * g + 2], a3 = sc[X][4 * g + 3];
        asm("v_cvt_pk_bf16_f32 %0, %1, %2" : "=v"(lo) : "v"(a0), "v"(a1));
        asm("v_cvt_pk_bf16_f32 %0, %1, %2" : "=v"(hi) : "v"(a2), "v"(a3));
        w[X * 8 + g * 2] = lo; w[X * 8 + g * 2 + 1] = hi;
      }
    }
    bf16x8 pa[8];
#pragma unroll
    for (int s = 0; s < 8; ++s) {
      int wb = (s >> 1) * 8 + (s & 1) * 4;
      uint32_t le = w[wb], he = w[wb + 1], lo_ = w[wb + 2], ho = w[wb + 3];
      asm("v_permlane32_swap_b32 %0, %1" : "+v"(le), "+v"(lo_));
      asm("v_permlane32_swap_b32 %0, %1" : "+v"(he), "+v"(ho));
      u32x4 fr = {le, he, lo_, ho};
      pa[s] = __builtin_bit_cast(bf16x8, fr);
    }

    // ---- wait V(t) (drains to 4: K(t+1) stays in flight), then barrier
    asm volatile("s_waitcnt vmcnt(4)" ::: "memory");
    __builtin_amdgcn_sched_barrier(0);
    __builtin_amdgcn_s_barrier();          // BAR-mid: V(t) visible
    __builtin_amdgcn_sched_barrier(0);

    // ---- PV: O[q][d] += P[q][k] V[k][d], k 0..127 in 8 slots
    const char* vbp = (const char*)Vs;
    __builtin_amdgcn_s_setprio(1);
#pragma unroll
    for (int db = 0; db < 4; ++db) {
      int d = db * 32 + l31;
      int fv = ((d & 7) ^ ((d >> 3) & 7)) & 7;
#pragma unroll
      for (int ks = 0; ks < 8; ++ks) {
        bf16x8 vv = *reinterpret_cast<const bf16x8*>(
            vbp + (ks >> 2) * 16384 + d * 128 + ((((ks & 3) * 2 + hh) ^ fv) << 4));
        oacc[db] = __builtin_amdgcn_mfma_f32_32x32x16_bf16(pa[ks], vv, oacc[db], 0, 0, 0);
      }
    }
    __builtin_amdgcn_s_setprio(0);

    __builtin_amdgcn_sched_barrier(0);
    __builtin_amdgcn_s_barrier();          // BAR2: Vs + Ks[cur] reads done
    __builtin_amdgcn_sched_barrier(0);
  }

  // ---- epilogue: reduce l across halves, normalize, store
  lrow += __shfl_xor(lrow, 32);
  float inv_[16];
#pragma unroll
  for (int r = 0; r < 16; ++r) {
    int qr = (r & 3) + 8 * (r >> 2) + 4 * hh;
    inv_[r] = 1.0f / __shfl(lrow, qr);
  }
#pragma unroll
  for (int db = 0; db < 4; ++db) {
#pragma unroll
    for (int r = 0; r < 16; ++r) {
      int qr = (r & 3) + 8 * (r >> 2) + 4 * hh;
      O[qbase + (size_t)(q0w + qr) * D_DIM + db * 32 + l31] =
          f2bf(oacc[db][r] * inv_[r]);
    }
  }
}

// ---------------- launch ----------------
extern "C" void kernel_launch(void* const* d_in, const int* in_sizes, int n_in,
                              void* d_out, int out_size, void* d_ws, size_t ws_size,
                              hipStream_t stream) {
  const float* x   = (const float*)d_in[0];
  const float* fc  = (const float*)d_in[1];
  const float* fs  = (const float*)d_in[2];
  const float* qw  = (const float*)d_in[3];
  const float* qb  = (const float*)d_in[4];
  const float* kw  = (const float*)d_in[5];
  const float* kb  = (const float*)d_in[6];
  const float* vw  = (const float*)d_in[7];
  const float* vb  = (const float*)d_in[8];
  const float* ow  = (const float*)d_in[9];
  const float* ob  = (const float*)d_in[10];
  const float* qnw = (const float*)d_in[11];
  const float* knw = (const float*)d_in[12];
  float* out = (float*)d_out;

  const size_t MSD = (size_t)MROWS * D_DIM;
  const size_t WSZ = (size_t)D_DIM * D_DIM;
  char* ws = (char*)d_ws;
  unsigned short* xb   = (unsigned short*)ws; ws += MSD * 2;
  unsigned short* qwb  = (unsigned short*)ws; ws += WSZ * 2;   // qwb,kwb,vwb contiguous
  unsigned short* kwb  = (unsigned short*)ws; ws += WSZ * 2;   //   = Bt[6144][2048]
  unsigned short* vwb  = (unsigned short*)ws; ws += WSZ * 2;
  unsigned short* owb  = (unsigned short*)ws; ws += WSZ * 2;
  unsigned short* qpre = (unsigned short*)ws; ws += MSD * 2;   // bf16 pre-norm Q
  unsigned short* kpre = (unsigned short*)ws; ws += MSD * 2;   // bf16 pre-norm K
  unsigned short* qb16 = (unsigned short*)ws; ws += MSD * 2;
  unsigned short* kb16 = (unsigned short*)ws; ws += MSD * 2;   // Kh[b][h][s][d]
  unsigned short* vt16 = (unsigned short*)ws; ws += MSD * 2;   // Vt2[b][h][s/64][d][s%64]
  unsigned short* ob16 = (unsigned short*)ws; ws += MSD * 2;

  cast_all<<<2048, 256, 0, stream>>>(x, qw, kw, vw, ow, xb, qwb, kwb, vwb, owb);

  // fused QKV projection: M=4096, N=6144, K=2048 -> 1536 blocks (~5/CU)
  gemm_bt<3><<<dim3((MROWS / 128) * (3 * D_DIM / 128)), 256, 0, stream>>>(
      xb, qwb, qb, kb, vb, qpre, kpre, vt16, MROWS, 3 * D_DIM, D_DIM);

  const float qscale = 0.08838834764831845f * 1.4426950408889634f;
  norm_rope2<<<2 * MROWS, 256, 0, stream>>>(qpre, kpre, qnw, knw, fc, fs,
                                            qb16, kb16, qscale);

  attn_kernel<<<dim3(S_LEN / 256 * NHEAD * B_SZ), 512, 0, stream>>>(qb16, kb16, vt16, ob16);

  // output projection: M=4096, N=2048 -> 512 blocks
  gemm_bt<0><<<dim3((MROWS / 128) * (D_DIM / 128)), 256, 0, stream>>>(
      ob16, owb, ob, nullptr, nullptr, out, nullptr, nullptr, MROWS, D_DIM, D_DIM);
}